// Round 7
// baseline (354.889 us; speedup 1.0000x reference)
//
#include <hip/hip_runtime.h>
#include <hip/hip_bf16.h>

typedef __attribute__((ext_vector_type(8))) short bf16x8;
typedef __attribute__((ext_vector_type(4))) float f32x4;
typedef __attribute__((ext_vector_type(2))) unsigned u32x2;

#define NB 8
#define C1 256
#define HH 192
#define WW 192
#define GH 48
#define GW 48
#define NP 2304
#define KSEL 576
#define RH 64
#define HID 128
#define C4 1024
#define HW (HH*WW)

// ---- workspace layout (byte offsets) ----
#define WS_FLAG 0
#define WS_F 64
#define WS_W16 81280ull
#define WS_POOLED 605696ull
#define WS_PSCALE WS_POOLED
#define WS_SCORES 19480064ull

// ---- float-index offsets inside F section ----
#define F_RW1 0
#define F_RG1 16384
#define F_RB1 16448
#define F_RW2 16512
#define F_RBIAS2 16576
#define F_EG1 16580
#define F_EB1 16708
#define F_DWW 16836
#define F_DWG 17988
#define F_DWB 18116
#define F_EG2 18244
#define F_EB2 19268

__device__ __forceinline__ float b2f(unsigned short h) {
  return __uint_as_float(((unsigned)h) << 16);
}
__device__ __forceinline__ unsigned short f2b(float f) {
  unsigned u = __float_as_uint(f);
  u += 0x7FFF + ((u >> 16) & 1u);
  return (unsigned short)(u >> 16);
}
__device__ __forceinline__ unsigned pkbf(float a, float b) {
  unsigned r;
  asm("v_cvt_pk_bf16_f32 %0, %1, %2" : "=v"(r) : "v"(a), "v"(b));
  return r;
}
__device__ __forceinline__ float siluf(float v) { return v / (1.f + expf(-v)); }

// ---- dtype detector ----
__global__ void k_detect(const unsigned short* xb, char* ws) {
  __shared__ int cnt[256];
  int t = threadIdx.x;
  int c = 0;
#pragma unroll
  for (int s = 0; s < 8; ++s) {
    unsigned short u = xb[(size_t)(t * 8 + s) * 1024];
    int e = (u >> 7) & 0xFF;
    c += (u == 0 || (e >= 90 && e <= 145)) ? 1 : 0;
  }
  cnt[t] = c;
  __syncthreads();
  for (int s = 128; s > 0; s >>= 1) {
    if (t < s) cnt[t] += cnt[t + s];
    __syncthreads();
  }
  if (t == 0) *(int*)(ws + WS_FLAG) = (cnt[0] >= 1229) ? 1 : 0;
}

// ---- weight prep ----
__global__ void k_prep(const void* rw1, const void* rg1, const void* rb1, const void* rw2,
                       const void* rbias2, const void* ew1, const void* eg1, const void* eb1,
                       const void* dww, const void* dwg, const void* dwb, const void* ew2,
                       const void* eg2, const void* eb2, char* ws) {
  int bf = *(const int*)(ws + WS_FLAG);
  float* F = (float*)(ws + WS_F);
  unsigned short* W16 = (unsigned short*)(ws + WS_W16);
  int i = blockIdx.x * 256 + threadIdx.x;
  if (i >= 282433) return;
  if (i < 20289) {
    const void* src; int si; int dof;
    if      (i < 16384) { src = rw1;    si = i;          dof = F_RW1 + si; }
    else if (i < 16448) { src = rg1;    si = i - 16384;  dof = F_RG1 + si; }
    else if (i < 16512) { src = rb1;    si = i - 16448;  dof = F_RB1 + si; }
    else if (i < 16576) { src = rw2;    si = i - 16512;  dof = F_RW2 + si; }
    else if (i < 16577) { src = rbias2; si = i - 16576;  dof = F_RBIAS2 + si; }
    else if (i < 16705) { src = eg1;    si = i - 16577;  dof = F_EG1 + si; }
    else if (i < 16833) { src = eb1;    si = i - 16705;  dof = F_EB1 + si; }
    else if (i < 17985) { src = dww;    si = i - 16833;  dof = F_DWW + si; }
    else if (i < 18113) { src = dwg;    si = i - 17985;  dof = F_DWG + si; }
    else if (i < 18241) { src = dwb;    si = i - 18113;  dof = F_DWB + si; }
    else if (i < 19265) { src = eg2;    si = i - 18241;  dof = F_EG2 + si; }
    else                { src = eb2;    si = i - 19265;  dof = F_EB2 + si; }
    F[dof] = bf ? b2f(((const unsigned short*)src)[si]) : ((const float*)src)[si];
  } else {
    int j = i - 20289;
    const void* src; int si; int dof;
    if (j < 131072) { src = ew1; si = j;          dof = j; }
    else            { src = ew2; si = j - 131072; dof = j; }
    W16[dof] = bf ? ((const unsigned short*)src)[si]
                  : f2b(((const float*)src)[si]);
  }
}

// ---- 4x4 avg pool (order-preserving -> identical selection) ----
__global__ void k_pool(const void* xin, char* ws) {
  const int bf = *(const int*)(ws + WS_FLAG);
  float* pooled = (float*)(ws + WS_POOLED);
  int tid = blockIdx.x * 256 + threadIdx.x;
  int px = tid % GW;
  int t2 = tid / GW;
  int py = t2 % GH;
  int bc = t2 / GH;
  size_t base = (size_t)bc * HW + (size_t)(py * 4) * WW + px * 4;
  float s = 0.f;
  if (bf) {
#pragma unroll
    for (int r = 0; r < 4; ++r) {
      const ushort4 v = *(const ushort4*)((const unsigned short*)xin + base + r * WW);
      s += b2f(v.x) + b2f(v.y) + b2f(v.z) + b2f(v.w);
    }
  } else {
#pragma unroll
    for (int r = 0; r < 4; ++r) {
      const float4 v = *(const float4*)((const float*)xin + base + r * WW);
      s += v.x + v.y + v.z + v.w;
    }
  }
  pooled[tid] = s * 0.0625f;
}

// ---- router MLP (unchanged, proven) ----
__global__ __launch_bounds__(512, 2) void k_mlp(char* ws) {
  const float* F = (const float*)(ws + WS_F);
  const float* pooled = (const float*)(ws + WS_POOLED);
  float* scores = (float*)(ws + WS_SCORES);
  __shared__ float LP[256][68];
  __shared__ float LR[8 * 64];
  const int t = threadIdx.x;
  const int b = blockIdx.x / 36;
  const int pos0 = (blockIdx.x % 36) * 64;
  {
    const int pc = t & 15, c0 = t >> 4;
    const float* src = pooled + (size_t)(b * C1) * NP + pos0 + pc * 4;
#pragma unroll
    for (int s = 0; s < 8; ++s) {
      int c = c0 + 32 * s;
      float4 v = *(const float4*)(src + (size_t)c * NP);
      *(float4*)&LP[c][pc * 4] = v;
    }
  }
  __syncthreads();
  const int lane = t & 63;
  const int q = __builtin_amdgcn_readfirstlane(t >> 6);
  const float* wq = F + F_RW1 + q * 8 * C1;
  float acc[8];
#pragma unroll
  for (int j = 0; j < 8; ++j) acc[j] = 0.f;
  for (int c = 0; c < 256; c += 4) {
    float p0 = LP[c + 0][lane];
    float p1 = LP[c + 1][lane];
    float p2 = LP[c + 2][lane];
    float p3 = LP[c + 3][lane];
#pragma unroll
    for (int j = 0; j < 8; ++j) {
      acc[j] += wq[j * C1 + c + 0] * p0;
      acc[j] += wq[j * C1 + c + 1] * p1;
      acc[j] += wq[j * C1 + c + 2] * p2;
      acc[j] += wq[j * C1 + c + 3] * p3;
    }
  }
  const float BNS = 1.f / sqrtf(1.f + 1e-5f);
  float lp = 0.f;
#pragma unroll
  for (int j = 0; j < 8; ++j) {
    int h = q * 8 + j;
    float v = acc[j] * (F[F_RG1 + h] * BNS) + F[F_RB1 + h];
    lp += F[F_RW2 + h] * siluf(v);
  }
  LR[q * 64 + lane] = lp;
  __syncthreads();
  if (t < 64) {
    float s = F[F_RBIAS2];
#pragma unroll
    for (int j = 0; j < 8; ++j) s += LR[j * 64 + t];
    scores[b * NP + pos0 + t] = 1.f / (1.f + expf(-s));
  }
}

// ---- per-patch scale ----
__global__ void k_route(char* ws) {
  const float* scores = (const float*)(ws + WS_SCORES);
  float* pscale = (float*)(ws + WS_PSCALE);
  int b = blockIdx.x / 9, r = blockIdx.x % 9;
  __shared__ float s[NP];
  for (int i = threadIdx.x; i < NP; i += 256) s[i] = scores[b * NP + i];
  __syncthreads();
  int i = r * 256 + threadIdx.x;
  float si = s[i];
  int rank = 0;
  for (int j = 0; j < NP; ++j) {
    float sj = s[j];
    rank += (sj > si || (sj == si && j < i)) ? 1 : 0;
  }
  pscale[b * NP + i] = (rank < KSEL) ? si : 0.f;
}

// ======================= dense expert, 128x128 GEMM1 tile =======================
// block: 2 patch-rows x 16 patches (N=128). n = rh*64 + (pr*2+pc)*16 + patch.

#define MM(A_, B_, C_) C_ = __builtin_amdgcn_mfma_f32_16x16x32_bf16(A_, B_, C_, 0, 0, 0)

#define XLOAD(P_, cc_) do { \
    size_t o_ = (size_t)(cc_) * 16 * HW; \
    if (BF) { \
      if (sel0) { *(ushort4*)&P_##f00 = *(const ushort4*)(xh + xoff00 + o_); \
                  *(ushort4*)&P_##f10 = *(const ushort4*)(xh + xoff10 + o_); } \
      if (sel1) { *(ushort4*)&P_##f01 = *(const ushort4*)(xh + xoff01 + o_); \
                  *(ushort4*)&P_##f11 = *(const ushort4*)(xh + xoff11 + o_); } \
    } else { \
      if (sel0) { P_##f00 = *(const float4*)(xf + xoff00 + o_); \
                  P_##f10 = *(const float4*)(xf + xoff10 + o_); } \
      if (sel1) { P_##f01 = *(const float4*)(xf + xoff01 + o_); \
                  P_##f11 = *(const float4*)(xf + xoff11 + o_); } \
    } \
    const unsigned short* wp_ = W1b + (cc_) * 64; \
    P_##w0 = *(const uint4*)(wp_ + wi0); \
    P_##w1 = *(const uint4*)(wp_ + wi1); \
  } while(0)

#define XWRITE(P_, UT_, WC_) do { \
    unsigned q00_, q01_, q10_, q11_, q20_, q21_, q30_, q31_; \
    if (BF) { \
      ushort4 u0_ = *(ushort4*)&P_##f00, u1_ = *(ushort4*)&P_##f01; \
      ushort4 u2_ = *(ushort4*)&P_##f10, u3_ = *(ushort4*)&P_##f11; \
      q00_ = u0_.x | ((unsigned)u0_.y << 16); q01_ = u0_.z | ((unsigned)u0_.w << 16); \
      q10_ = u1_.x | ((unsigned)u1_.y << 16); q11_ = u1_.z | ((unsigned)u1_.w << 16); \
      q20_ = u2_.x | ((unsigned)u2_.y << 16); q21_ = u2_.z | ((unsigned)u2_.w << 16); \
      q30_ = u3_.x | ((unsigned)u3_.y << 16); q31_ = u3_.z | ((unsigned)u3_.w << 16); \
    } else { \
      q00_ = pkbf(P_##f00.x, P_##f00.y); q01_ = pkbf(P_##f00.z, P_##f00.w); \
      q10_ = pkbf(P_##f01.x, P_##f01.y); q11_ = pkbf(P_##f01.z, P_##f01.w); \
      q20_ = pkbf(P_##f10.x, P_##f10.y); q21_ = pkbf(P_##f10.z, P_##f10.w); \
      q30_ = pkbf(P_##f11.x, P_##f11.y); q31_ = pkbf(P_##f11.z, P_##f11.w); \
    } \
    *(unsigned*)&UT_[n00_72 + kb0] = q00_; \
    *(unsigned*)&UT_[n01_72 + kb0] = q01_; \
    *(unsigned*)&UT_[n10_72 + kb0] = q10_; \
    *(unsigned*)&UT_[n11_72 + kb0] = q11_; \
    *(unsigned*)&UT_[n00_72 + kb1] = q20_; \
    *(unsigned*)&UT_[n01_72 + kb1] = q21_; \
    *(unsigned*)&UT_[n10_72 + kb1] = q30_; \
    *(unsigned*)&UT_[n11_72 + kb1] = q31_; \
    *(uint4*)&WC_[wcw0] = P_##w0; \
    *(uint4*)&WC_[wcw1] = P_##w1; \
  } while(0)

#define G1_MFMA(UT_, WCp_) do { \
    const unsigned short* WC_ = WCp_; \
    bf16x8 b00_ = *(const bf16x8*)&UT_[ut0_off]; \
    bf16x8 b10_ = *(const bf16x8*)&UT_[ut1_off]; \
    bf16x8 b01_ = *(const bf16x8*)&UT_[ut0_off + 32]; \
    bf16x8 b11_ = *(const bf16x8*)&UT_[ut1_off + 32]; \
    bf16x8 a_; \
    a_ = *(const bf16x8*)&WC_[wc_off];          MM(a_, b00_, acc00); MM(a_, b10_, acc01); \
    a_ = *(const bf16x8*)&WC_[wc_off + 1152];   MM(a_, b00_, acc10); MM(a_, b10_, acc11); \
    a_ = *(const bf16x8*)&WC_[wc_off + 2304];   MM(a_, b00_, acc20); MM(a_, b10_, acc21); \
    a_ = *(const bf16x8*)&WC_[wc_off + 3456];   MM(a_, b00_, acc30); MM(a_, b10_, acc31); \
    a_ = *(const bf16x8*)&WC_[wc_off + 32];     MM(a_, b01_, acc00); MM(a_, b11_, acc01); \
    a_ = *(const bf16x8*)&WC_[wc_off + 1184];   MM(a_, b01_, acc10); MM(a_, b11_, acc11); \
    a_ = *(const bf16x8*)&WC_[wc_off + 2336];   MM(a_, b01_, acc20); MM(a_, b11_, acc21); \
    a_ = *(const bf16x8*)&WC_[wc_off + 3488];   MM(a_, b01_, acc30); MM(a_, b11_, acc31); \
  } while(0)

#define G1EPI(A0_, A1_, mi_) do { \
    const int h0_ = 64 * wm + 16 * (mi_) + l4 * 4; \
    float g0_ = F[F_EG1 + h0_] * BNS,     c0_ = F[F_EB1 + h0_]; \
    float g1_ = F[F_EG1 + h0_ + 1] * BNS, c1_ = F[F_EB1 + h0_ + 1]; \
    float g2_ = F[F_EG1 + h0_ + 2] * BNS, c2_ = F[F_EB1 + h0_ + 2]; \
    float g3_ = F[F_EG1 + h0_ + 3] * BNS, c3_ = F[F_EB1 + h0_ + 3]; \
    unsigned lo0_ = pkbf(siluf(A0_[0] * g0_ + c0_), siluf(A0_[1] * g1_ + c1_)); \
    unsigned hi0_ = pkbf(siluf(A0_[2] * g2_ + c2_), siluf(A0_[3] * g3_ + c3_)); \
    unsigned lo1_ = pkbf(siluf(A1_[0] * g0_ + c0_), siluf(A1_[1] * g1_ + c1_)); \
    unsigned hi1_ = pkbf(siluf(A1_[2] * g2_ + c2_), siluf(A1_[3] * g3_ + c3_)); \
    *(u32x2*)&O1b[(32 * wn + l15) * 136 + h0_] = (u32x2){lo0_, hi0_}; \
    *(u32x2*)&O1b[(32 * wn + 16 + l15) * 136 + h0_] = (u32x2){lo1_, hi1_}; \
  } while(0)

#define G2_STEP(P_, WCp_, mt_) do { \
    const unsigned short* WC_ = (const unsigned short*)(WCp_); \
    *(uint4*)&((unsigned short*)(WCp_))[w2a] = P_##a; \
    *(uint4*)&((unsigned short*)(WCp_))[w2b] = P_##b; \
    if ((mt_) < 14) { \
      const unsigned short* wp_ = W2b + (size_t)((mt_) + 2) * 8192; \
      P_##a = *(const uint4*)(wp_ + w2s); \
      P_##b = *(const uint4*)(wp_ + w2s + 64); \
    } \
    __syncthreads(); \
    f32x4 c00_ = (f32x4){0.f,0.f,0.f,0.f}; \
    f32x4 c01_ = (f32x4){0.f,0.f,0.f,0.f}; \
    f32x4 c10_ = (f32x4){0.f,0.f,0.f,0.f}; \
    f32x4 c11_ = (f32x4){0.f,0.f,0.f,0.f}; \
    { bf16x8 a0_, a1_; \
      a0_ = *(const bf16x8*)&WC_[g2_off];        a1_ = *(const bf16x8*)&WC_[g2_off + 2176]; \
      MM(a0_, bq00, c00_); MM(a0_, bq10, c01_); MM(a1_, bq00, c10_); MM(a1_, bq10, c11_); \
      a0_ = *(const bf16x8*)&WC_[g2_off + 32];   a1_ = *(const bf16x8*)&WC_[g2_off + 2208]; \
      MM(a0_, bq01, c00_); MM(a0_, bq11, c01_); MM(a1_, bq01, c10_); MM(a1_, bq11, c11_); \
      a0_ = *(const bf16x8*)&WC_[g2_off + 64];   a1_ = *(const bf16x8*)&WC_[g2_off + 2240]; \
      MM(a0_, bq02, c00_); MM(a0_, bq12, c01_); MM(a1_, bq02, c10_); MM(a1_, bq12, c11_); \
      a0_ = *(const bf16x8*)&WC_[g2_off + 96];   a1_ = *(const bf16x8*)&WC_[g2_off + 2272]; \
      MM(a0_, bq03, c00_); MM(a0_, bq13, c01_); MM(a1_, bq03, c10_); MM(a1_, bq13, c11_); \
    } \
    _Pragma("unroll") \
    for (int r_ = 0; r_ < 4; ++r_) { \
      int ml0_ = 32 * wm + l4 * 4 + r_; \
      int m20_ = (mt_) * 64 + ml0_; \
      float g0_ = F[F_EG2 + m20_] * BNS,      d0_ = F[F_EB2 + m20_]; \
      float g1_ = F[F_EG2 + m20_ + 16] * BNS, d1_ = F[F_EB2 + m20_ + 16]; \
      OT[ml0_ * 132 + otn0]             = c00_[r_] * g0_ + d0_; \
      OT[ml0_ * 132 + otn0 + 16]        = c01_[r_] * g0_ + d0_; \
      OT[(ml0_ + 16) * 132 + otn0]      = c10_[r_] * g1_ + d1_; \
      OT[(ml0_ + 16) * 132 + otn0 + 16] = c11_[r_] * g1_ + d1_; \
    } \
    __syncthreads(); \
    _Pragma("unroll") \
    for (int s_ = 0; s_ < 4; ++s_) { \
      int chl_ = st_cg + 4 * s_; \
      int ch_ = (mt_) * 16 + chl_; \
      int mlb_ = chl_ * 4 + st_dr * 2; \
      float e0_ = OT[mlb_ * 132 + st_nb] * psv; \
      float e1_ = OT[(mlb_ + 1) * 132 + st_nb] * psv; \
      float e2_ = OT[mlb_ * 132 + st_nb + 16] * psv; \
      float e3_ = OT[(mlb_ + 1) * 132 + st_nb + 16] * psv; \
      size_t ob_ = ((size_t)(bC1 + ch_) * HH + r0 + st_row) * WW + c0 + st_p * 4; \
      if (BF) { ushort4 o4_ = {f2b(e0_), f2b(e1_), f2b(e2_), f2b(e3_)}; \
                *(ushort4*)((unsigned short*)outv + ob_) = o4_; } \
      else    { float4 o4_ = {e0_, e1_, e2_, e3_}; \
                *(float4*)((float*)outv + ob_) = o4_; } \
    } \
    __syncthreads(); \
  } while(0)

__global__ __launch_bounds__(512, 4) void k_expert(const void* xin, void* outv, char* ws) {
  const int BF = *(const int*)(ws + WS_FLAG);
  const float* F = (const float*)(ws + WS_F);
  const unsigned short* W1b = (const unsigned short*)(ws + WS_W16);
  const unsigned short* W2b = W1b + 131072;
  const float* pscale = (const float*)(ws + WS_PSCALE);

  // LDS union (73856 B total -> 2 blocks/CU):
  // GEMM1: UT0,UT1 (2x18432) + WC0,WC1 (2x18432)
  // epi:   O1b bf16 [128n][136h] @0 (34816) ; dw out Y2T @36864 (34816)
  // GEMM2: WC20 @0, WC21 @17408 (2x17408) ; OT fp32 [64m][132n] @36864 (33792)
  __shared__ __align__(16) char LB[73856];
  unsigned short* UT0  = (unsigned short*)(LB);
  unsigned short* UT1  = (unsigned short*)(LB + 18432);
  unsigned short* WC0  = (unsigned short*)(LB + 36864);
  unsigned short* WC1  = (unsigned short*)(LB + 55296);
  unsigned short* O1b  = (unsigned short*)(LB);
  unsigned short* Y2T  = (unsigned short*)(LB + 36864);
  unsigned short* WC20 = (unsigned short*)(LB);
  unsigned short* WC21 = (unsigned short*)(LB + 17408);
  float*          OT   = (float*)(LB + 36864);
  float*          PSs  = (float*)(LB + 73728);

  const int t = threadIdx.x;
  const int lane = t & 63;
  const int w = t >> 6;
  const int wm = w >> 2, wn = w & 3;
  const int l15 = lane & 15, l4 = lane >> 4;
  const int bid = blockIdx.x;
  const int xq = bid % 3;
  const int pyq = (bid / 3) % 24;
  const int b  = bid / 72;
  const int r0 = pyq * 8, c0 = xq * 64;
  const int bC1 = b * C1;
  const float BNS = 1.f / sqrtf(1.f + 1e-5f);

  if (t < 32) PSs[t] = pscale[b * NP + (pyq * 2 + (t >> 4)) * GW + xq * 16 + (t & 15)];
  __syncthreads();

  // staging coords
  const int rr = (t >> 4) & 3, v4 = t & 15;
  const bool sel0 = PSs[v4] != 0.f;
  const bool sel1 = PSs[16 + v4] != 0.f;
  const int n00_72 = ((rr >> 1) * 32 + v4) * 72;   // rh0 pc0
  const int n01_72 = n00_72 + 16 * 72;             // rh0 pc1
  const int n10_72 = n00_72 + 64 * 72;             // rh1 pc0
  const int n11_72 = n10_72 + 16 * 72;             // rh1 pc1
  const int kb0 = 4 * w + 2 * (rr & 1);
  const int kb1 = kb0 + 32;
  const size_t xoff00 = ((size_t)bC1 + w) * HW + (size_t)(r0 + rr) * WW + c0 + v4 * 4;
  const size_t xoff01 = xoff00 + 4 * WW;
  const size_t xoff10 = xoff00 + (size_t)8 * HW;
  const size_t xoff11 = xoff10 + 4 * WW;
  const int m_0 = t >> 3, k8_0 = t & 7;
  const int wi0 = m_0 * 1024 + k8_0 * 8;
  const int wi1 = (m_0 + 64) * 1024 + k8_0 * 8;
  const int wcw0 = m_0 * 72 + k8_0 * 8;
  const int wcw1 = (m_0 + 64) * 72 + k8_0 * 8;
  // GEMM1 mfma coords
  const int ut0_off = (32 * wn + l15) * 72 + l4 * 8;
  const int ut1_off = ut0_off + 16 * 72;
  const int wc_off = (64 * wm + l15) * 72 + l4 * 8;
  // GEMM2 coords
  const int w2a = (t >> 3) * 136 + (t & 7) * 8;
  const int w2b = w2a + 64;
  const int w2s = (t >> 3) * 128 + (t & 7) * 8;
  const int g2_off = (32 * wm + l15) * 136 + l4 * 8;
  const int otn0 = 32 * wn + l15;
  // store coords
  const int st_p = t & 15, st_row = (t >> 4) & 7, st_cg = t >> 7;
  const int st_rh = st_row >> 2, st_pr = (st_row >> 1) & 1, st_dr = st_row & 1;
  const int st_nb = st_rh * 64 + st_pr * 32 + st_p;
  const float psv = PSs[st_rh * 16 + st_p];

  const float* xf = (const float*)xin;
  const unsigned short* xh = (const unsigned short*)xin;

  // named staging registers (zero-init; unselected lanes keep zeros)
  float4 Af00 = {0,0,0,0}, Af01 = {0,0,0,0}, Af10 = {0,0,0,0}, Af11 = {0,0,0,0};
  float4 Bf00 = {0,0,0,0}, Bf01 = {0,0,0,0}, Bf10 = {0,0,0,0}, Bf11 = {0,0,0,0};
  uint4 Aw0, Aw1, Bw0, Bw1;
  uint4 A2a, A2b, B2a, B2b;

  f32x4 acc00 = (f32x4){0.f,0.f,0.f,0.f}, acc01 = acc00;
  f32x4 acc10 = acc00, acc11 = acc00;
  f32x4 acc20 = acc00, acc21 = acc00;
  f32x4 acc30 = acc00, acc31 = acc00;

  // ---- GEMM1: 16 K-chunks, LDS double-buffered ----
  XLOAD(A, 0);
  XLOAD(B, 1);
  for (int cc2 = 0; cc2 < 8; ++cc2) {
    int cc = cc2 * 2;
    XWRITE(A, UT0, WC0);
    if (cc2 < 7) XLOAD(A, cc + 2);
    __syncthreads();
    G1_MFMA(UT0, WC0);
    XWRITE(B, UT1, WC1);
    if (cc2 < 7) XLOAD(B, cc + 3);
    __syncthreads();
    G1_MFMA(UT1, WC1);
  }

  // prefetch GEMM2 weight tiles 0,1
  A2a = *(const uint4*)(W2b + w2s);
  A2b = *(const uint4*)(W2b + w2s + 64);
  B2a = *(const uint4*)(W2b + 8192 + w2s);
  B2b = *(const uint4*)(W2b + 8192 + w2s + 64);

  __syncthreads();               // GEMM1 LDS reads done (O1b aliases UT)
  G1EPI(acc00, acc01, 0);
  G1EPI(acc10, acc11, 1);
  G1EPI(acc20, acc21, 2);
  G1EPI(acc30, acc31, 3);
  __syncthreads();

  // ---- depthwise 3x3 on 2x2 + BN + SiLU: O1b -> Y2T (both [n][136h] bf16) ----
  {
    const int dh = t & 127;
    const int dgrp = t >> 7;
    const float* kw = F + F_DWW + dh * 9;
    float k0 = kw[0], k1 = kw[1], k2 = kw[2], k3 = kw[3], k4 = kw[4];
    float k5 = kw[5], k6 = kw[6], k7 = kw[7], k8 = kw[8];
    float sd = F[F_DWG + dh] * BNS, bd = F[F_DWB + dh];
#pragma unroll
    for (int s = 0; s < 8; ++s) {
      int combo = dgrp * 8 + s;
      int patch = combo & 15, rh = combo >> 4;
      int nb = (rh * 64 + patch) * 136 + dh;
      float i0 = b2f(O1b[nb]);
      float i1 = b2f(O1b[nb + 16 * 136]);
      float i2 = b2f(O1b[nb + 32 * 136]);
      float i3 = b2f(O1b[nb + 48 * 136]);
      float o00 = k4 * i0 + k5 * i1 + k7 * i2 + k8 * i3;
      float o01 = k3 * i0 + k4 * i1 + k6 * i2 + k7 * i3;
      float o10 = k1 * i0 + k2 * i1 + k4 * i2 + k5 * i3;
      float o11 = k0 * i0 + k1 * i1 + k3 * i2 + k4 * i3;
      Y2T[nb] = f2b(siluf(o00 * sd + bd));
      Y2T[nb + 16 * 136] = f2b(siluf(o01 * sd + bd));
      Y2T[nb + 32 * 136] = f2b(siluf(o10 * sd + bd));
      Y2T[nb + 48 * 136] = f2b(siluf(o11 * sd + bd));
    }
  }
  __syncthreads();

  // ---- GEMM2: 16 M-tiles of 64; B-frags (2 nj x 4 ks) preloaded in regs ----
  const int yb0 = (32 * wn + l15) * 136 + l4 * 8;
  const int yb1 = yb0 + 16 * 136;
  bf16x8 bq00 = *(const bf16x8*)&Y2T[yb0];
  bf16x8 bq01 = *(const bf16x8*)&Y2T[yb0 + 32];
  bf16x8 bq02 = *(const bf16x8*)&Y2T[yb0 + 64];
  bf16x8 bq03 = *(const bf16x8*)&Y2T[yb0 + 96];
  bf16x8 bq10 = *(const bf16x8*)&Y2T[yb1];
  bf16x8 bq11 = *(const bf16x8*)&Y2T[yb1 + 32];
  bf16x8 bq12 = *(const bf16x8*)&Y2T[yb1 + 64];
  bf16x8 bq13 = *(const bf16x8*)&Y2T[yb1 + 96];

  for (int mtt = 0; mtt < 16; mtt += 2) {
    G2_STEP(A2, WC20, mtt);
    G2_STEP(B2, WC21, mtt + 1);
  }
}

extern "C" void kernel_launch(void* const* d_in, const int* in_sizes, int n_in,
                              void* d_out, int out_size, void* d_ws, size_t ws_size,
                              hipStream_t stream) {
  char* ws = (char*)d_ws;
  const void* x = d_in[0];
  k_detect<<<1, 256, 0, stream>>>((const unsigned short*)x, ws);
  k_prep<<<1104, 256, 0, stream>>>(d_in[1], d_in[2], d_in[3], d_in[4], d_in[5], d_in[6],
                                   d_in[7], d_in[8], d_in[9], d_in[10], d_in[11], d_in[12],
                                   d_in[13], d_in[14], ws);
  k_pool<<<18432, 256, 0, stream>>>(x, ws);
  k_mlp<<<288, 512, 0, stream>>>(ws);
  k_route<<<72, 256, 0, stream>>>(ws);
  k_expert<<<576, 512, 0, stream>>>(x, d_out, ws);
}